// Round 3
// baseline (248.595 us; speedup 1.0000x reference)
//
#include <hip/hip_runtime.h>
#include <hip/hip_bf16.h>

// KAN layer = GEMM: out[b,o] = sum_{i,k} T_k(tanh(x[b,i])) * W[o,i,k] + bias[o]
// Round-3 structure: NO LDS, NO barriers. Prep writes A and B in MFMA
// fragment order; GEMM streams fragments global->VGPR->MFMA.
//
// Fragment order (16x16x32 bf16 MFMA, verified layouts):
//   A-frag: lane L holds A[m = L&15][k = (L>>4)*8 + j], j=0..7
//   B-frag: lane L holds B[n = L&15][k = (L>>4)*8 + j]   (B^T GEMM)
//   C/D   : col = lane&15, row = (lane>>4)*4 + r
// Storage: A_swz[mt][kb][lane][8] bf16, mt=0..255 (4096/16), kb=0..255 (8192/32)
//          B_swz[nt][kb][lane][8] bf16, nt=0..63  (1024/16)
#define MD 4096
#define ND 1024
#define KD 8192
#define IN_F 1024
#define KBLKS (KD / 32)  // 256
#define MT (MD / 16)     // 256
#define NT (ND / 16)     // 64

typedef __bf16 bf16x8 __attribute__((ext_vector_type(8)));
typedef float f32x4 __attribute__((ext_vector_type(4)));

// ---------------- Prep: basis+convert directly into fragment layout --------
#define N_A (MT * KBLKS * 64)  // 4.19M threads, one x element each
#define N_B (NT * KBLKS * 64)  // 1.05M threads, 8 w floats each

__global__ __launch_bounds__(256) void prep_kernel(
    const float* __restrict__ x, const float* __restrict__ w,
    __bf16* __restrict__ A, __bf16* __restrict__ B) {
  int t = blockIdx.x * blockDim.x + threadIdx.x;
  if (t < N_A) {
    // decode: lane L, k-block kb, m-tile mt
    int L = t & 63;
    int kb = (t >> 6) & (KBLKS - 1);
    int mt = t >> 14;
    int b = mt * 16 + (L & 15);
    int i = kb * 4 + (L >> 4);
    float v = x[(size_t)b * IN_F + i];
    float tt = tanhf(v);
    float two_t = 2.0f * tt;
    float T0 = 1.0f;
    float T1 = tt;
    float T2 = two_t * T1 - T0;
    float T3 = two_t * T2 - T1;
    float T4 = two_t * T3 - T2;
    float T5 = two_t * T4 - T3;
    float T6 = two_t * T5 - T4;
    float T7 = two_t * T6 - T5;
    bf16x8 o;
    o[0] = (__bf16)T0; o[1] = (__bf16)T1; o[2] = (__bf16)T2; o[3] = (__bf16)T3;
    o[4] = (__bf16)T4; o[5] = (__bf16)T5; o[6] = (__bf16)T6; o[7] = (__bf16)T7;
    *(bf16x8*)(A + (size_t)t * 8) = o;  // coalesced 16B store
  } else if (t < N_A + N_B) {
    int j = t - N_A;
    int L = j & 63;
    int kb = (j >> 6) & (KBLKS - 1);
    int nt = j >> 14;
    int o_ = nt * 16 + (L & 15);
    int i = kb * 4 + (L >> 4);
    const float4* p = (const float4*)(w + ((size_t)o_ * IN_F + i) * 8);
    float4 a = p[0], b = p[1];
    bf16x8 v;
    v[0] = (__bf16)a.x; v[1] = (__bf16)a.y; v[2] = (__bf16)a.z; v[3] = (__bf16)a.w;
    v[4] = (__bf16)b.x; v[5] = (__bf16)b.y; v[6] = (__bf16)b.z; v[7] = (__bf16)b.w;
    *(bf16x8*)(B + (size_t)j * 8) = v;  // coalesced 16B store
  }
}

// ---------------- GEMM: register-direct fragments, no LDS, no barriers -----
// Block = 256 thr = 4 waves (2x2), wave tile 64x64 (4x4 of 16x16x32),
// block tile 128x128. Grid (8, 32) = 256 blocks.
__global__ __launch_bounds__(256) void gemm_reg(
    const __bf16* __restrict__ A, const __bf16* __restrict__ B,
    const float* __restrict__ bias, float* __restrict__ C) {
  const int tid = threadIdx.x;
  const int wave = tid >> 6;
  const int lane = tid & 63;
  const int wm = wave >> 1;  // 0..1
  const int wn = wave & 1;   // 0..1
  const int mt0 = blockIdx.y * 8 + wm * 4;  // wave's first m-tile
  const int nt0 = blockIdx.x * 8 + wn * 4;  // wave's first n-tile

  // per-fragment stream pointers: frag(tile, kb) at ((tile*KBLKS + kb)*64 + lane)*8
  const __bf16* pa[4];
  const __bf16* pb[4];
#pragma unroll
  for (int i = 0; i < 4; i++) {
    pa[i] = A + (((size_t)(mt0 + i) * KBLKS) * 64 + lane) * 8;
    pb[i] = B + (((size_t)(nt0 + i) * KBLKS) * 64 + lane) * 8;
  }

  f32x4 acc[4][4];
#pragma unroll
  for (int i = 0; i < 4; i++)
#pragma unroll
    for (int j = 0; j < 4; j++) acc[i][j] = (f32x4){0.f, 0.f, 0.f, 0.f};

  // register double-buffer over kb
  bf16x8 a0[4], b0[4], a1[4], b1[4];
#pragma unroll
  for (int i = 0; i < 4; i++) {
    a0[i] = *(const bf16x8*)(pa[i]);
    b0[i] = *(const bf16x8*)(pb[i]);
  }

  for (int kb = 0; kb < KBLKS - 2; kb += 2) {
    // prefetch kb+1
#pragma unroll
    for (int i = 0; i < 4; i++) {
      a1[i] = *(const bf16x8*)(pa[i] + (size_t)(kb + 1) * 512);
      b1[i] = *(const bf16x8*)(pb[i] + (size_t)(kb + 1) * 512);
    }
    // compute kb
#pragma unroll
    for (int mi = 0; mi < 4; mi++)
#pragma unroll
      for (int ni = 0; ni < 4; ni++)
        acc[mi][ni] = __builtin_amdgcn_mfma_f32_16x16x32_bf16(
            a0[mi], b0[ni], acc[mi][ni], 0, 0, 0);
    // prefetch kb+2
#pragma unroll
    for (int i = 0; i < 4; i++) {
      a0[i] = *(const bf16x8*)(pa[i] + (size_t)(kb + 2) * 512);
      b0[i] = *(const bf16x8*)(pb[i] + (size_t)(kb + 2) * 512);
    }
    // compute kb+1
#pragma unroll
    for (int mi = 0; mi < 4; mi++)
#pragma unroll
      for (int ni = 0; ni < 4; ni++)
        acc[mi][ni] = __builtin_amdgcn_mfma_f32_16x16x32_bf16(
            a1[mi], b1[ni], acc[mi][ni], 0, 0, 0);
  }
  // tail: kb = KBLKS-2, KBLKS-1
  {
    const int kb = KBLKS - 2;
#pragma unroll
    for (int i = 0; i < 4; i++) {
      a1[i] = *(const bf16x8*)(pa[i] + (size_t)(kb + 1) * 512);
      b1[i] = *(const bf16x8*)(pb[i] + (size_t)(kb + 1) * 512);
    }
#pragma unroll
    for (int mi = 0; mi < 4; mi++)
#pragma unroll
      for (int ni = 0; ni < 4; ni++)
        acc[mi][ni] = __builtin_amdgcn_mfma_f32_16x16x32_bf16(
            a0[mi], b0[ni], acc[mi][ni], 0, 0, 0);
#pragma unroll
    for (int mi = 0; mi < 4; mi++)
#pragma unroll
      for (int ni = 0; ni < 4; ni++)
        acc[mi][ni] = __builtin_amdgcn_mfma_f32_16x16x32_bf16(
            a1[mi], b1[ni], acc[mi][ni], 0, 0, 0);
  }

  // ---- epilogue: C/D layout col=lane&15, row=(lane>>4)*4+r ; add bias
  const int m0 = blockIdx.y * 128 + wm * 64;
  const int n0 = blockIdx.x * 128 + wn * 64;
  const int row0 = m0 + (lane >> 4) * 4;
#pragma unroll
  for (int ni = 0; ni < 4; ni++) {
    int col = n0 + ni * 16 + (lane & 15);
    float bv = bias[col];
#pragma unroll
    for (int mi = 0; mi < 4; mi++) {
      int row = row0 + mi * 16;
#pragma unroll
      for (int r = 0; r < 4; r++)
        C[(size_t)(row + r) * ND + col] = acc[mi][ni][r] + bv;
    }
  }
}

extern "C" void kernel_launch(void* const* d_in, const int* in_sizes, int n_in,
                              void* d_out, int out_size, void* d_ws, size_t ws_size,
                              hipStream_t stream) {
  const float* x = (const float*)d_in[0];     // [4096,1024]
  const float* w = (const float*)d_in[1];     // [1024,1024,8]
  const float* bias = (const float*)d_in[2];  // [1024]
  float* out = (float*)d_out;                 // [4096,1024]

  __bf16* Abf = (__bf16*)d_ws;                                 // 64 MB
  __bf16* Bbf = (__bf16*)((char*)d_ws + (size_t)MD * KD * 2);  // 16 MB

  {
    int n = N_A + N_B;
    prep_kernel<<<(n + 255) / 256, 256, 0, stream>>>(x, w, Abf, Bbf);
  }
  {
    dim3 grid(ND / 128, MD / 128);  // (8, 32) = 256 blocks, 1/CU
    gemm_reg<<<grid, 256, 0, stream>>>(Abf, Bbf, bias, out);
  }
}

// Round 4
// 240.714 us; speedup vs baseline: 1.0327x; 1.0327x over previous
//
#include <hip/hip_runtime.h>
#include <hip/hip_bf16.h>

// KAN layer = GEMM: out[b,o] = sum_{i,k} T_k(tanh(x[b,i])) * W[o,i,k] + bias[o]
//   A (basis) : [4096, 8192] bf16 row-major (built in ws)
//   B (weights): [1024, 8192] bf16 row-major (converted in ws) -> gemm_bt
// Round-4: 128x128 block tile, BK=64, DOUBLE-BUFFERED LDS (stage k+1 during
// compute of k), XOR-swizzled LDS (proven 0 conflicts), 4 waves 2x2,
// wave tile 64x64 = 4x4 of 16x16x32 bf16 MFMA.
#define MD 4096
#define ND 1024
#define KD 8192
#define IN_F 1024

typedef __bf16 bf16x8 __attribute__((ext_vector_type(8)));
typedef float f32x4 __attribute__((ext_vector_type(4)));

// ---------------- Prep (merged): basis + W convert, row-major bf16 ----------
#define N_BASIS (MD * IN_F)
#define N_CONV ((ND * KD) / 8)

__global__ __launch_bounds__(256) void prep_kernel(
    const float* __restrict__ x, const float* __restrict__ w,
    __bf16* __restrict__ A, __bf16* __restrict__ B) {
  int i = blockIdx.x * blockDim.x + threadIdx.x;
  if (i < N_BASIS) {
    float t = tanhf(x[i]);
    float two_t = 2.0f * t;
    float T0 = 1.0f;
    float T1 = t;
    float T2 = two_t * T1 - T0;
    float T3 = two_t * T2 - T1;
    float T4 = two_t * T3 - T2;
    float T5 = two_t * T4 - T3;
    float T6 = two_t * T5 - T4;
    float T7 = two_t * T6 - T5;
    bf16x8 v;
    v[0] = (__bf16)T0; v[1] = (__bf16)T1; v[2] = (__bf16)T2; v[3] = (__bf16)T3;
    v[4] = (__bf16)T4; v[5] = (__bf16)T5; v[6] = (__bf16)T6; v[7] = (__bf16)T7;
    *(bf16x8*)(A + (size_t)i * 8) = v;
  } else if (i < N_BASIS + N_CONV) {
    int j = i - N_BASIS;
    const float4* p = (const float4*)(w + (size_t)j * 8);
    float4 a = p[0], b = p[1];
    bf16x8 v;
    v[0] = (__bf16)a.x; v[1] = (__bf16)a.y; v[2] = (__bf16)a.z; v[3] = (__bf16)a.w;
    v[4] = (__bf16)b.x; v[5] = (__bf16)b.y; v[6] = (__bf16)b.z; v[7] = (__bf16)b.w;
    *(bf16x8*)(B + (size_t)j * 8) = v;
  }
}

// ---------------- GEMM_BT + bias, double-buffered LDS ----------------
#define BM 128
#define BN 128
#define BK 64
#define KITERS (KD / BK)  // 128

__global__ __launch_bounds__(256) void gemm_bias(
    const __bf16* __restrict__ A, const __bf16* __restrict__ B,
    const float* __restrict__ bias, float* __restrict__ C) {
  // 2 buffers x (128 rows A + 128 rows B) x 64 bf16 = 2 x 32 KB = 64 KB
  __shared__ __align__(16) __bf16 As[2][BM * BK];
  __shared__ __align__(16) __bf16 Bs[2][BN * BK];

  const int tid = threadIdx.x;
  const int wave = tid >> 6;
  const int lane = tid & 63;
  const int n0 = blockIdx.x * BN;
  const int m0 = blockIdx.y * BM;
  const int wm = wave >> 1;  // 0..1 (row half)
  const int wn = wave & 1;   // 0..1 (col half)

  // ---- staging: global_load_lds 16B/lane, one instr = 8 rows x 128 B.
  // XOR swizzle on the global side: physical slot (row, pg) holds logical
  // group pg^ (row&7); preserves per-row coalescing exactly.
  const int ar = lane >> 3;                   // 0..7
  const int swz_col = ((lane & 7) ^ ar) * 8;  // swizzled 8-elem column group
  const __bf16* gA = A + (size_t)(m0 + wave * 32 + ar) * KD + swz_col;
  const __bf16* gB = B + (size_t)(n0 + wave * 32 + ar) * KD + swz_col;
  const int ldsOffA = (wave * 32) * BK;  // wave stages 32 rows of A
  const int ldsOffB = (wave * 32) * BK;  // and 32 rows of B

  f32x4 acc[4][4];
#pragma unroll
  for (int i = 0; i < 4; i++)
#pragma unroll
    for (int j = 0; j < 4; j++) acc[i][j] = (f32x4){0.f, 0.f, 0.f, 0.f};

  // ---- fragment coords (16x16x32: m=lane&15, k=(lane>>4)*8+j)
  const int fr = lane & 15;
  const int fr7 = fr & 7;
  const int qk = lane >> 4;  // 0..3

  // prologue: stage k-tile 0 into buffer 0
#pragma unroll
  for (int j = 0; j < 4; j++) {
    __builtin_amdgcn_global_load_lds(
        (const __attribute__((address_space(1))) void*)(gA + (size_t)j * 8 * KD),
        (__attribute__((address_space(3))) void*)(&As[0][ldsOffA + j * 8 * BK]),
        16, 0, 0);
    __builtin_amdgcn_global_load_lds(
        (const __attribute__((address_space(1))) void*)(gB + (size_t)j * 8 * KD),
        (__attribute__((address_space(3))) void*)(&Bs[0][ldsOffB + j * 8 * BK]),
        16, 0, 0);
  }
  __syncthreads();

#pragma unroll 2
  for (int kt = 0; kt < KITERS; kt++) {
    const int cur = kt & 1;
    const int nxt = cur ^ 1;
    // stage k-tile kt+1 into the other buffer (async; flies during compute)
    if (kt + 1 < KITERS) {
      const int g = (kt + 1) * BK;
#pragma unroll
      for (int j = 0; j < 4; j++) {
        __builtin_amdgcn_global_load_lds(
            (const __attribute__((address_space(1))) void*)(gA + g + (size_t)j * 8 * KD),
            (__attribute__((address_space(3))) void*)(&As[nxt][ldsOffA + j * 8 * BK]),
            16, 0, 0);
        __builtin_amdgcn_global_load_lds(
            (const __attribute__((address_space(1))) void*)(gB + g + (size_t)j * 8 * KD),
            (__attribute__((address_space(3))) void*)(&Bs[nxt][ldsOffB + j * 8 * BK]),
            16, 0, 0);
      }
    }
    // compute on current buffer
#pragma unroll
    for (int s = 0; s < 2; s++) {
      const int pa = ((s * 4 + qk) ^ fr7) * 8;  // swizzled physical group
      bf16x8 af[4], bfr[4];
#pragma unroll
      for (int mi = 0; mi < 4; mi++)
        af[mi] = *(const bf16x8*)&As[cur][(wm * 64 + mi * 16 + fr) * BK + pa];
#pragma unroll
      for (int ni = 0; ni < 4; ni++)
        bfr[ni] = *(const bf16x8*)&Bs[cur][(wn * 64 + ni * 16 + fr) * BK + pa];
#pragma unroll
      for (int mi = 0; mi < 4; mi++)
#pragma unroll
        for (int ni = 0; ni < 4; ni++)
          acc[mi][ni] = __builtin_amdgcn_mfma_f32_16x16x32_bf16(
              af[mi], bfr[ni], acc[mi][ni], 0, 0, 0);
    }
    // barrier: (a) all waves done reading cur, (b) drains vmcnt -> nxt ready.
    __syncthreads();
  }

  // ---- epilogue: C/D layout col=lane&15, row=(lane>>4)*4+r ; add bias
  const int row0 = m0 + wm * 64 + (lane >> 4) * 4;
  const int col0 = n0 + wn * 64;
#pragma unroll
  for (int ni = 0; ni < 4; ni++) {
    int col = col0 + ni * 16 + (lane & 15);
    float bv = bias[col];
#pragma unroll
    for (int mi = 0; mi < 4; mi++) {
      int row = row0 + mi * 16;
#pragma unroll
      for (int r = 0; r < 4; r++)
        C[(size_t)(row + r) * ND + col] = acc[mi][ni][r] + bv;
    }
  }
}

extern "C" void kernel_launch(void* const* d_in, const int* in_sizes, int n_in,
                              void* d_out, int out_size, void* d_ws, size_t ws_size,
                              hipStream_t stream) {
  const float* x = (const float*)d_in[0];     // [4096,1024]
  const float* w = (const float*)d_in[1];     // [1024,1024,8]
  const float* bias = (const float*)d_in[2];  // [1024]
  float* out = (float*)d_out;                 // [4096,1024]

  __bf16* Abf = (__bf16*)d_ws;                                 // 64 MB
  __bf16* Bbf = (__bf16*)((char*)d_ws + (size_t)MD * KD * 2);  // 16 MB

  {
    int n = N_BASIS + N_CONV;
    prep_kernel<<<(n + 255) / 256, 256, 0, stream>>>(x, w, Abf, Bbf);
  }
  {
    dim3 grid(ND / BN, MD / BM);  // (8, 32) = 256 blocks, 1/CU
    gemm_bias<<<grid, 256, 0, stream>>>(Abf, Bbf, bias, out);
  }
}

// Round 5
// 218.249 us; speedup vs baseline: 1.1390x; 1.1029x over previous
//
#include <hip/hip_runtime.h>
#include <hip/hip_bf16.h>

// KAN layer = GEMM: out[b,o] = sum_{i,k} T_k(tanh(x[b,i])) * W[o,i,k] + bias[o]
//   A (basis) : [4096, 8192] bf16 row-major (built in ws)
//   B (weights): [1024, 8192] bf16 row-major (converted in ws) -> gemm_bt
// Round-5: r2 geometry (BM=64,BN=128,BK=64; 512 blocks = 2 blocks/CU,
// 8 waves/CU for latency hiding) + DOUBLE-BUFFERED LDS (48 KB) to overlap
// the VMEM staging phase (853 cyc/CU/iter) with the LDS-read/MFMA phase
// (1129 cyc). XOR swizzle keeps bank conflicts at 0 (verified r2).
#define MD 4096
#define ND 1024
#define KD 8192
#define IN_F 1024

typedef __bf16 bf16x8 __attribute__((ext_vector_type(8)));
typedef float f32x4 __attribute__((ext_vector_type(4)));

// ---------------- Prep (merged): basis + W convert, row-major bf16 ----------
#define N_BASIS (MD * IN_F)
#define N_CONV ((ND * KD) / 8)

__global__ __launch_bounds__(256) void prep_kernel(
    const float* __restrict__ x, const float* __restrict__ w,
    __bf16* __restrict__ A, __bf16* __restrict__ B) {
  int i = blockIdx.x * blockDim.x + threadIdx.x;
  if (i < N_BASIS) {
    float t = tanhf(x[i]);
    float two_t = 2.0f * t;
    float T0 = 1.0f;
    float T1 = t;
    float T2 = two_t * T1 - T0;
    float T3 = two_t * T2 - T1;
    float T4 = two_t * T3 - T2;
    float T5 = two_t * T4 - T3;
    float T6 = two_t * T5 - T4;
    float T7 = two_t * T6 - T5;
    bf16x8 v;
    v[0] = (__bf16)T0; v[1] = (__bf16)T1; v[2] = (__bf16)T2; v[3] = (__bf16)T3;
    v[4] = (__bf16)T4; v[5] = (__bf16)T5; v[6] = (__bf16)T6; v[7] = (__bf16)T7;
    *(bf16x8*)(A + (size_t)i * 8) = v;
  } else if (i < N_BASIS + N_CONV) {
    int j = i - N_BASIS;
    const float4* p = (const float4*)(w + (size_t)j * 8);
    float4 a = p[0], b = p[1];
    bf16x8 v;
    v[0] = (__bf16)a.x; v[1] = (__bf16)a.y; v[2] = (__bf16)a.z; v[3] = (__bf16)a.w;
    v[4] = (__bf16)b.x; v[5] = (__bf16)b.y; v[6] = (__bf16)b.z; v[7] = (__bf16)b.w;
    *(bf16x8*)(B + (size_t)j * 8) = v;
  }
}

// ---------------- GEMM_BT + bias: 64x128 tile, double-buffered LDS ---------
#define BM 64
#define BN 128
#define BK 64
#define KITERS (KD / BK)  // 128

__global__ __launch_bounds__(256) void gemm_bias(
    const __bf16* __restrict__ A, const __bf16* __restrict__ B,
    const float* __restrict__ bias, float* __restrict__ C) {
  // 2 x (8 KB A + 16 KB B) = 48 KB
  __shared__ __align__(16) __bf16 As[2][BM * BK];
  __shared__ __align__(16) __bf16 Bs[2][BN * BK];

  const int tid = threadIdx.x;
  const int wave = tid >> 6;
  const int lane = tid & 63;
  const int n0 = blockIdx.x * BN;
  const int m0 = blockIdx.y * BM;
  const int wm = wave >> 1;  // 0..1
  const int wn = wave & 1;   // 0..1

  // ---- staging: global_load_lds 16B/lane; one instr covers 8 rows x 128B.
  // XOR swizzle on the global side: physical slot (row,pg) holds logical
  // group pg^(row&7); per-row coalescing preserved exactly.
  const int ar = lane >> 3;                   // 0..7
  const int swz_col = ((lane & 7) ^ ar) * 8;  // swizzled 8-elem column group
  const __bf16* gA = A + (size_t)(m0 + wave * 16 + ar) * KD + swz_col;
  const __bf16* gB = B + (size_t)(n0 + wave * 32 + ar) * KD + swz_col;
  const int offA = (wave * 16) * BK;  // wave stages 16 rows of A (2 instr)
  const int offB = (wave * 32) * BK;  // and 32 rows of B (4 instr)

  f32x4 acc[2][4];
#pragma unroll
  for (int i = 0; i < 2; i++)
#pragma unroll
    for (int j = 0; j < 4; j++) acc[i][j] = (f32x4){0.f, 0.f, 0.f, 0.f};

  // ---- fragment coords (16x16x32: m=lane&15, k=(lane>>4)*8+j)
  const int fr = lane & 15;
  const int fr7 = fr & 7;
  const int qk = lane >> 4;  // 0..3

  // prologue: stage k-tile 0 into buffer 0
#pragma unroll
  for (int j = 0; j < 2; j++)
    __builtin_amdgcn_global_load_lds(
        (const __attribute__((address_space(1))) void*)(gA + (size_t)j * 8 * KD),
        (__attribute__((address_space(3))) void*)(&As[0][offA + j * 8 * BK]),
        16, 0, 0);
#pragma unroll
  for (int j = 0; j < 4; j++)
    __builtin_amdgcn_global_load_lds(
        (const __attribute__((address_space(1))) void*)(gB + (size_t)j * 8 * KD),
        (__attribute__((address_space(3))) void*)(&Bs[0][offB + j * 8 * BK]),
        16, 0, 0);
  __syncthreads();

#pragma unroll 2
  for (int kt = 0; kt < KITERS; kt++) {
    const int cur = kt & 1;
    const int nxt = cur ^ 1;
    // stage k-tile kt+1 into the other buffer; loads fly during compute and
    // are drained by the compiler's vmcnt(0) before the end-of-iter barrier.
    if (kt + 1 < KITERS) {
      const int g = (kt + 1) * BK;
#pragma unroll
      for (int j = 0; j < 2; j++)
        __builtin_amdgcn_global_load_lds(
            (const __attribute__((address_space(1))) void*)(gA + g + (size_t)j * 8 * KD),
            (__attribute__((address_space(3))) void*)(&As[nxt][offA + j * 8 * BK]),
            16, 0, 0);
#pragma unroll
      for (int j = 0; j < 4; j++)
        __builtin_amdgcn_global_load_lds(
            (const __attribute__((address_space(1))) void*)(gB + g + (size_t)j * 8 * KD),
            (__attribute__((address_space(3))) void*)(&Bs[nxt][offB + j * 8 * BK]),
            16, 0, 0);
    }
    // compute on current buffer
#pragma unroll
    for (int s = 0; s < 2; s++) {
      const int pa = ((s * 4 + qk) ^ fr7) * 8;  // swizzled physical group
      bf16x8 af[2], bfr[4];
#pragma unroll
      for (int mi = 0; mi < 2; mi++)
        af[mi] = *(const bf16x8*)&As[cur][(wm * 32 + mi * 16 + fr) * BK + pa];
#pragma unroll
      for (int ni = 0; ni < 4; ni++)
        bfr[ni] = *(const bf16x8*)&Bs[cur][(wn * 64 + ni * 16 + fr) * BK + pa];
#pragma unroll
      for (int mi = 0; mi < 2; mi++)
#pragma unroll
        for (int ni = 0; ni < 4; ni++)
          acc[mi][ni] = __builtin_amdgcn_mfma_f32_16x16x32_bf16(
              af[mi], bfr[ni], acc[mi][ni], 0, 0, 0);
    }
    // one barrier per iter: waves done reading cur; vmcnt drained -> nxt ready;
    // iter kt+1 may then overwrite cur.
    __syncthreads();
  }

  // ---- epilogue: C/D layout col=lane&15, row=(lane>>4)*4+r ; add bias
  const int col0 = n0 + wn * 64;
  const int row0 = m0 + wm * 32 + (lane >> 4) * 4;
#pragma unroll
  for (int ni = 0; ni < 4; ni++) {
    int col = col0 + ni * 16 + (lane & 15);
    float bv = bias[col];
#pragma unroll
    for (int mi = 0; mi < 2; mi++) {
      int row = row0 + mi * 16;
#pragma unroll
      for (int r = 0; r < 4; r++)
        C[(size_t)(row + r) * ND + col] = acc[mi][ni][r] + bv;
    }
  }
}

extern "C" void kernel_launch(void* const* d_in, const int* in_sizes, int n_in,
                              void* d_out, int out_size, void* d_ws, size_t ws_size,
                              hipStream_t stream) {
  const float* x = (const float*)d_in[0];     // [4096,1024]
  const float* w = (const float*)d_in[1];     // [1024,1024,8]
  const float* bias = (const float*)d_in[2];  // [1024]
  float* out = (float*)d_out;                 // [4096,1024]

  __bf16* Abf = (__bf16*)d_ws;                                 // 64 MB
  __bf16* Bbf = (__bf16*)((char*)d_ws + (size_t)MD * KD * 2);  // 16 MB

  {
    int n = N_BASIS + N_CONV;
    prep_kernel<<<(n + 255) / 256, 256, 0, stream>>>(x, w, Abf, Bbf);
  }
  {
    dim3 grid(ND / BN, MD / BM);  // (8, 64) = 512 blocks -> 2 blocks/CU
    gemm_bias<<<grid, 256, 0, stream>>>(Abf, Bbf, bias, out);
  }
}